// Round 4
// baseline (198.585 us; speedup 1.0000x reference)
//
#include <hip/hip_runtime.h>
#include <hip/hip_bf16.h>
#include <stdint.h>

#define HIDDEN 128

typedef __attribute__((ext_vector_type(8))) short short8;
typedef __attribute__((ext_vector_type(4))) unsigned uint4v;
typedef __attribute__((ext_vector_type(4))) float float4v;
typedef __attribute__((ext_vector_type(2))) float float2v;
typedef __attribute__((ext_vector_type(2))) unsigned uint2v;

static __device__ __forceinline__ unsigned short f2bf(float f) {
    union { float f; unsigned u; } v; v.f = f;
    unsigned r = (v.u + 0x7FFFu + ((v.u >> 16) & 1u)) >> 16;
    return (unsigned short)r;
}

// RNE-pack two f32 into one dword of bf16 (lo = f0, hi = f1): 5 VALU.
static __device__ __forceinline__ unsigned pack2bf(float f0, float f1) {
    unsigned u0 = __float_as_uint(f0), u1 = __float_as_uint(f1);
    u0 = u0 + 0x7FFFu + ((u0 >> 16) & 1u);
    u1 = u1 + 0x7FFFu + ((u1 >> 16) & 1u);
    // result bytes [u0.b2, u0.b3, u1.b2, u1.b3]; perm: sel<4 -> S1(=u0), >=4 -> S0(=u1)
    return __builtin_amdgcn_perm(u1, u0, 0x07060302u);
}

static __device__ __forceinline__ short8 pack8(float4v lo, float4v hi) {
    uint4v u;
    u[0] = pack2bf(lo[0], lo[1]);
    u[1] = pack2bf(lo[2], lo[3]);
    u[2] = pack2bf(hi[0], hi[1]);
    u[3] = pack2bf(hi[2], hi[3]);
    return *(short8*)&u;
}

// Kernel 1: build Wt (logical col-major combined weight, bf16) + permuted b1/W2.
// Combined W[k][j]: j<128 -> W1[k*128+j]; j>=128 -> W1[(128+k)*128+(j-128)]
// Wt[j*128+k] = W[k][j]. Permutation within each half: physical pp=m*8+tt <-> logical jj=tt*16+m.
__global__ void prep_wt(const float* __restrict__ W1, const float* __restrict__ b1,
                        const float* __restrict__ W2,
                        unsigned short* __restrict__ Wt,
                        float* __restrict__ b1p, float* __restrict__ W2p) {
    int idx = blockIdx.x * blockDim.x + threadIdx.x;   // 0 .. 32767
    if (idx < 256 * 128) {
        int j = idx >> 7, k = idx & 127;
        float v = (j < 128) ? W1[k * 128 + j] : W1[(128 + k) * 128 + (j - 128)];
        Wt[idx] = f2bf(v);
    }
    if (idx < 128) {
        int m = idx >> 3, tt = idx & 7;
        int jj = tt * 16 + m;
        b1p[idx] = b1[jj];
        W2p[idx] = W2[jj];
    }
}

// Kernel 2: Q[node][0:256] = z[node] @ W (+ b1 folded into first half), bf16, permuted layout.
// B-resident: wave w owns cols [w*64, w*64+64) in registers; block streams 128 nodes
// through 8 m-tiles with explicit next-tile z prefetch.
__global__ __launch_bounds__(256) void node_gemm(
        const float* __restrict__ z, const unsigned short* __restrict__ Wt,
        const float* __restrict__ b1p,
        unsigned short* __restrict__ Q, int n_nodes) {
    int lane = threadIdx.x & 63;
    int wave = threadIdx.x >> 6;
    int m = lane & 15;
    int quad = lane >> 4;
    int blockBase = blockIdx.x * 128;

    // B fragments, loaded once: cols wave*64 + t*16 + m
    short8 b[4][4];
    #pragma unroll
    for (int t = 0; t < 4; ++t) {
        const unsigned short* wp = Wt + (size_t)(wave * 64 + t * 16 + m) * HIDDEN;
        #pragma unroll
        for (int s = 0; s < 4; ++s)
            b[t][s] = *(const short8*)(wp + s * 32 + quad * 8);
    }

    int h   = wave >> 1;                      // 0: P1 half (bias folded), 1: P2 half
    int pp0 = m * 8 + (wave & 1) * 4;
    float4v b1v = (float4v)(0.0f);
    if (h == 0) b1v = *(const float4v*)(b1p + pp0);

    const float* zbase = z + (size_t)(blockBase + m) * HIDDEN + quad * 8;

    float4v raw[8];
    {
        bool ok = (blockBase + m) < n_nodes;
        #pragma unroll
        for (int s = 0; s < 4; ++s) {
            raw[2 * s]     = ok ? *(const float4v*)(zbase + s * 32)     : (float4v)(0.0f);
            raw[2 * s + 1] = ok ? *(const float4v*)(zbase + s * 32 + 4) : (float4v)(0.0f);
        }
    }

    #pragma unroll
    for (int it = 0; it < 8; ++it) {
        // prefetch next tile's raw z while we compute this one
        float4v nxt[8];
        if (it < 7) {
            bool ok = (blockBase + (it + 1) * 16 + m) < n_nodes;
            const float* zn = zbase + (size_t)(it + 1) * 16 * HIDDEN;
            #pragma unroll
            for (int s = 0; s < 4; ++s) {
                nxt[2 * s]     = ok ? *(const float4v*)(zn + s * 32)     : (float4v)(0.0f);
                nxt[2 * s + 1] = ok ? *(const float4v*)(zn + s * 32 + 4) : (float4v)(0.0f);
            }
        }

        short8 a[4];
        #pragma unroll
        for (int s = 0; s < 4; ++s) a[s] = pack8(raw[2 * s], raw[2 * s + 1]);

        float4v acc[4];
        #pragma unroll
        for (int t = 0; t < 4; ++t) acc[t] = (float4v)(0.0f);
        #pragma unroll
        for (int t = 0; t < 4; ++t)
            #pragma unroll
            for (int s = 0; s < 4; ++s)
                acc[t] = __builtin_amdgcn_mfma_f32_16x16x32_bf16(a[s], b[t][s], acc[t], 0, 0, 0);

        // C/D: node-row = quad*4 + r; lane's 4 col-tiles are contiguous at physical pp0.
        int n0 = blockBase + it * 16;
        #pragma unroll
        for (int r = 0; r < 4; ++r) {
            int node = n0 + quad * 4 + r;
            if (node < n_nodes) {
                float v0 = acc[0][r] + b1v[0];
                float v1 = acc[1][r] + b1v[1];
                float v2 = acc[2][r] + b1v[2];
                float v3 = acc[3][r] + b1v[3];
                uint2v pk;
                pk[0] = pack2bf(v0, v1);
                pk[1] = pack2bf(v2, v3);
                *(uint2v*)(Q + (size_t)node * 256 + h * 128 + pp0) = pk;
            }
        }

        if (it < 7) {
            #pragma unroll
            for (int j = 0; j < 8; ++j) raw[j] = nxt[j];
        }
    }
}

// Kernel 3: out[e] = sum_pp relu(Q[r][pp] + Q[c][128+pp]) * W2p[pp] + b2  (b1 pre-folded)
// 16 lanes per edge, 4 edges per group; all 8 gathers issued before any math.
__global__ __launch_bounds__(256) void edge_kernel(
        const int* __restrict__ eli, const unsigned short* __restrict__ Q,
        const float* __restrict__ W2p, const float* __restrict__ b2,
        float* __restrict__ out, int E) {
    int g      = threadIdx.x >> 4;
    int lane16 = threadIdx.x & 15;
    int j0 = lane16 * 8;

    float2v w[4];
    #pragma unroll
    for (int k = 0; k < 4; ++k) w[k] = ((const float2v*)(W2p + j0))[k];
    float bias2 = b2[0];

    int e0 = blockIdx.x * 64 + g;

    int idx_r[4], idx_c[4];
    #pragma unroll
    for (int i = 0; i < 4; ++i) {
        int e = e0 + i * 16;
        idx_r[i] = (e < E) ? eli[e]     : 0;
        idx_c[i] = (e < E) ? eli[E + e] : 0;
    }

    uint4v u1[4], u2[4];
    #pragma unroll
    for (int i = 0; i < 4; ++i) {
        u1[i] = *(const uint4v*)(Q + (size_t)idx_r[i] * 256 + j0);
        u2[i] = *(const uint4v*)(Q + (size_t)idx_c[i] * 256 + 128 + j0);
    }

    #pragma unroll
    for (int i = 0; i < 4; ++i) {
        float2v accv = (float2v)(0.0f);
        #pragma unroll
        for (int k = 0; k < 4; ++k) {
            unsigned a1 = u1[i][k], a2 = u2[i][k];
            float2v v1, v2;
            v1[0] = __uint_as_float(a1 << 16);
            v1[1] = __uint_as_float(a1 & 0xFFFF0000u);
            v2[0] = __uint_as_float(a2 << 16);
            v2[1] = __uint_as_float(a2 & 0xFFFF0000u);
            float2v s = v1 + v2;                       // v_pk_add_f32
            s[0] = fmaxf(s[0], 0.0f);
            s[1] = fmaxf(s[1], 0.0f);                  // v_pk_max_f32
            accv[0] = fmaf(s[0], w[k][0], accv[0]);
            accv[1] = fmaf(s[1], w[k][1], accv[1]);    // v_pk_fma_f32
        }
        float acc = accv[0] + accv[1];
        acc += __shfl_xor(acc, 1);
        acc += __shfl_xor(acc, 2);
        acc += __shfl_xor(acc, 4);
        acc += __shfl_xor(acc, 8);

        int e = e0 + i * 16;
        if (lane16 == 0 && e < E) out[e] = acc + bias2;
    }
}

extern "C" void kernel_launch(void* const* d_in, const int* in_sizes, int n_in,
                              void* d_out, int out_size, void* d_ws, size_t ws_size,
                              hipStream_t stream) {
    const float* z   = (const float*)d_in[0];
    const int*   eli = (const int*)d_in[1];
    const float* W1  = (const float*)d_in[2];
    const float* b1  = (const float*)d_in[3];
    const float* W2  = (const float*)d_in[4];
    const float* b2  = (const float*)d_in[5];
    int n_nodes = in_sizes[0] / HIDDEN;       // 100000
    int E       = in_sizes[1] / 2;            // 1000000
    float* out  = (float*)d_out;

    size_t qbytes = (size_t)n_nodes * 256 * 2;
    unsigned short* Q   = (unsigned short*)d_ws;
    unsigned short* Wt  = (unsigned short*)((char*)d_ws + qbytes);
    float*          b1p = (float*)((char*)d_ws + qbytes + 256 * 128 * 2);
    float*          W2p = b1p + 128;

    prep_wt<<<128, 256, 0, stream>>>(W1, b1, W2, Wt, b1p, W2p);

    node_gemm<<<(n_nodes + 127) / 128, 256, 0, stream>>>(z, Wt, b1p, Q, n_nodes);

    edge_kernel<<<(E + 63) / 64, 256, 0, stream>>>(eli, Q, W2p, b2, out, E);
}